// Round 1
// baseline (253.051 us; speedup 1.0000x reference)
//
#include <hip/hip_runtime.h>

#define NT    256          // threads per block
#define HW    3136         // 56*56 spatial elements per row
#define HW4   784          // HW / 4 (float4 chunks)
#define KSEL  627          // int(0.2 * 3136)
#define CHUNK 13           // ceil(HW / NT) contiguous elements per thread (tie pass)

// Block-wide exclusive prefix scan over one value per thread (Hillis-Steele in LDS).
// Also returns the block total. Safe for back-to-back calls (trailing sync).
__device__ __forceinline__ unsigned int block_excl_scan(unsigned int v, unsigned int* tmp,
                                                        int tid, unsigned int* total) {
    tmp[tid] = v;
    __syncthreads();
    for (int off = 1; off < NT; off <<= 1) {
        unsigned int t = (tid >= off) ? tmp[tid - off] : 0u;
        __syncthreads();
        tmp[tid] += t;
        __syncthreads();
    }
    unsigned int incl = tmp[tid];
    unsigned int tot  = tmp[NT - 1];
    __syncthreads();   // protect tmp reads from the next call's writes
    *total = tot;
    return incl - v;
}

// Given hist[NB] (counts per ascending bin) and target rank kprime (1-based, from the top),
// find bin B such that (#elements in bins > B) < kprime <= (#elements in bins >= B).
// Writes B to *s_bin and the strictly-greater count to *s_gt. Ends with a barrier.
template <int NB>
__device__ __forceinline__ void locate_bin(const unsigned int* hist, unsigned int kprime,
                                           unsigned int* tmp, volatile unsigned int* s_bin,
                                           volatile unsigned int* s_gt, int tid) {
    constexpr int PER = NB / NT;
    const int b0 = tid * PER;
    unsigned int s = 0;
#pragma unroll
    for (int j = 0; j < PER; ++j) s += hist[b0 + j];
    unsigned int total;
    unsigned int pre = block_excl_scan(s, tmp, tid, &total);
    unsigned int cum = total - pre - s;   // elements in bins above this thread's top bin
#pragma unroll
    for (int j = PER - 1; j >= 0; --j) {
        unsigned int h = hist[b0 + j];    // at this point cum = #elements with bin > b0+j
        if (cum < kprime && kprime <= cum + h) {
            *s_bin = (unsigned int)(b0 + j);
            *s_gt  = cum;
        }
        cum += h;
    }
    __syncthreads();
}

__global__ __launch_bounds__(NT) void topk_mask_kernel(const float* __restrict__ x,
                                                       float* __restrict__ out) {
    __shared__ uint4        sdata4[HW4];      // row as raw float bits (12.25 KB)
    __shared__ unsigned int hist[4096];       // radix histograms (16 KB)
    __shared__ unsigned int scan_tmp[NT];
    __shared__ unsigned int s_bin, s_gt;

    unsigned int* sdata = (unsigned int*)sdata4;
    const int tid = threadIdx.x;
    const size_t row = blockIdx.x;
    const float4* xr4 = (const float4*)(x + row * (size_t)HW);
    float4*       or4 = (float4*)(out + row * (size_t)HW);

    // ---- stage row into LDS (vectorized, coalesced) + clear histograms
    for (int i = tid; i < HW4; i += NT) {
        float4 v = xr4[i];
        sdata4[i] = make_uint4(__float_as_uint(v.x), __float_as_uint(v.y),
                               __float_as_uint(v.z), __float_as_uint(v.w));
    }
    for (int i = tid; i < 4096; i += NT) hist[i] = 0u;
    __syncthreads();

    // ---- radix-select pass 1: bits [30:20] (2048 bins)
    for (int i = tid; i < HW; i += NT) {
        unsigned int key = sdata[i] & 0x7fffffffu;
        atomicAdd(&hist[key >> 20], 1u);
    }
    __syncthreads();
    locate_bin<2048>(hist, KSEL, scan_tmp, &s_bin, &s_gt, tid);
    const unsigned int B1 = s_bin;
    const unsigned int G1 = s_gt;

    // ---- pass 2: bits [19:8] (4096 bins) restricted to bin B1
    for (int i = tid; i < 4096; i += NT) hist[i] = 0u;
    __syncthreads();
    const unsigned int k2 = KSEL - G1;
    for (int i = tid; i < HW; i += NT) {
        unsigned int key = sdata[i] & 0x7fffffffu;
        if ((key >> 20) == B1) atomicAdd(&hist[(key >> 8) & 0xfffu], 1u);
    }
    __syncthreads();
    locate_bin<4096>(hist, k2, scan_tmp, &s_bin, &s_gt, tid);
    const unsigned int B2 = s_bin;
    const unsigned int G2 = s_gt;

    // ---- pass 3: bits [7:0] (256 bins) restricted to (B1,B2)
    hist[tid] = 0u;                        // NT == 256 clears bins 0..255
    __syncthreads();
    const unsigned int k3   = k2 - G2;
    const unsigned int hi23 = (B1 << 12) | B2;   // compare against key >> 8
    for (int i = tid; i < HW; i += NT) {
        unsigned int key = sdata[i] & 0x7fffffffu;
        if ((key >> 8) == hi23) atomicAdd(&hist[key & 0xffu], 1u);
    }
    __syncthreads();
    locate_bin<256>(hist, k3, scan_tmp, &s_bin, &s_gt, tid);
    const unsigned int B3 = s_bin;
    const unsigned int G3 = s_gt;

    const unsigned int tkey = (hi23 << 8) | B3;  // exact k-th largest |x| bit pattern
    const unsigned int r    = k3 - G3;           // equals to keep, in index order (>= 1)

    // ---- tie-break exactly like lax.top_k: keep first r equal-valued elements by index.
    // Contiguous chunks per thread -> block scan gives index-ordered ranks of equals.
    {
        const int start = tid * CHUNK;
        const int end   = (start + CHUNK < HW) ? (start + CHUNK) : HW;
        unsigned int cnt = 0;
        for (int i = start; i < end; ++i)
            cnt += ((sdata[i] & 0x7fffffffu) == tkey) ? 1u : 0u;
        unsigned int total_eq;
        unsigned int base = block_excl_scan(cnt, scan_tmp, tid, &total_eq);
        unsigned int seen = 0;
        for (int i = start; i < end; ++i) {
            if ((sdata[i] & 0x7fffffffu) == tkey) {
                if (base + seen >= r) sdata[i] = 0u;   // drop: key becomes 0 < tkey
                ++seen;
            }
        }
    }
    __syncthreads();

    // ---- write output (vectorized, coalesced): keep iff |x| key >= threshold
    for (int i = tid; i < HW4; i += NT) {
        uint4 b = sdata4[i];
        float4 o;
        o.x = ((b.x & 0x7fffffffu) >= tkey) ? __uint_as_float(b.x) : 0.0f;
        o.y = ((b.y & 0x7fffffffu) >= tkey) ? __uint_as_float(b.y) : 0.0f;
        o.z = ((b.z & 0x7fffffffu) >= tkey) ? __uint_as_float(b.z) : 0.0f;
        o.w = ((b.w & 0x7fffffffu) >= tkey) ? __uint_as_float(b.w) : 0.0f;
        or4[i] = o;
    }
}

extern "C" void kernel_launch(void* const* d_in, const int* in_sizes, int n_in,
                              void* d_out, int out_size, void* d_ws, size_t ws_size,
                              hipStream_t stream) {
    const float* x = (const float*)d_in[0];
    float* out = (float*)d_out;
    const int rows = in_sizes[0] / HW;   // 32 * 256 = 8192
    topk_mask_kernel<<<rows, NT, 0, stream>>>(x, out);
}

// Round 2
// 196.119 us; speedup vs baseline: 1.2903x; 1.2903x over previous
//
#include <hip/hip_runtime.h>

#define NT   256
#define HW   3136          // 56*56
#define KSEL 627u          // int(0.2 * 3136)
#define CAP  512           // compaction list capacity

typedef unsigned int u32;
typedef unsigned long long u64;

// Count, across this wave, elements whose (key & msk) == tri.
// Keys carry full float bits; msk only covers bits [30:0] so the sign bit never matters.
__device__ __forceinline__ u32 cnt_match(uint4 v0, uint4 v1, uint4 v2, uint4 v3,
                                         bool tail, u32 msk, u32 tri) {
    u32 c = 0;
    c += __popcll(__ballot((v0.x & msk) == tri));
    c += __popcll(__ballot((v0.y & msk) == tri));
    c += __popcll(__ballot((v0.z & msk) == tri));
    c += __popcll(__ballot((v0.w & msk) == tri));
    c += __popcll(__ballot((v1.x & msk) == tri));
    c += __popcll(__ballot((v1.y & msk) == tri));
    c += __popcll(__ballot((v1.z & msk) == tri));
    c += __popcll(__ballot((v1.w & msk) == tri));
    c += __popcll(__ballot((v2.x & msk) == tri));
    c += __popcll(__ballot((v2.y & msk) == tri));
    c += __popcll(__ballot((v2.z & msk) == tri));
    c += __popcll(__ballot((v2.w & msk) == tri));
    c += __popcll(__ballot(tail && ((v3.x & msk) == tri)));
    c += __popcll(__ballot(tail && ((v3.y & msk) == tri)));
    c += __popcll(__ballot(tail && ((v3.z & msk) == tri)));
    c += __popcll(__ballot(tail && ((v3.w & msk) == tri)));
    return c;
}

// Count, across this wave, elements equal to tk (by |x| bits) with index <= mid.
__device__ __forceinline__ u32 cnt_eq_le(uint4 v0, uint4 v1, uint4 v2, uint4 v3,
                                         bool tail, u32 i0, u32 i1, u32 i2, u32 i3,
                                         u32 tk, u32 mid) {
    u32 c = 0;
    c += __popcll(__ballot(((v0.x & 0x7fffffffu) == tk) && (i0 + 0u) <= mid));
    c += __popcll(__ballot(((v0.y & 0x7fffffffu) == tk) && (i0 + 1u) <= mid));
    c += __popcll(__ballot(((v0.z & 0x7fffffffu) == tk) && (i0 + 2u) <= mid));
    c += __popcll(__ballot(((v0.w & 0x7fffffffu) == tk) && (i0 + 3u) <= mid));
    c += __popcll(__ballot(((v1.x & 0x7fffffffu) == tk) && (i1 + 0u) <= mid));
    c += __popcll(__ballot(((v1.y & 0x7fffffffu) == tk) && (i1 + 1u) <= mid));
    c += __popcll(__ballot(((v1.z & 0x7fffffffu) == tk) && (i1 + 2u) <= mid));
    c += __popcll(__ballot(((v1.w & 0x7fffffffu) == tk) && (i1 + 3u) <= mid));
    c += __popcll(__ballot(((v2.x & 0x7fffffffu) == tk) && (i2 + 0u) <= mid));
    c += __popcll(__ballot(((v2.y & 0x7fffffffu) == tk) && (i2 + 1u) <= mid));
    c += __popcll(__ballot(((v2.z & 0x7fffffffu) == tk) && (i2 + 2u) <= mid));
    c += __popcll(__ballot(((v2.w & 0x7fffffffu) == tk) && (i2 + 3u) <= mid));
    c += __popcll(__ballot(tail && ((v3.x & 0x7fffffffu) == tk) && (i3 + 0u) <= mid));
    c += __popcll(__ballot(tail && ((v3.y & 0x7fffffffu) == tk) && (i3 + 1u) <= mid));
    c += __popcll(__ballot(tail && ((v3.z & 0x7fffffffu) == tk) && (i3 + 2u) <= mid));
    c += __popcll(__ballot(tail && ((v3.w & 0x7fffffffu) == tk) && (i3 + 3u) <= mid));
    return c;
}

__global__ __launch_bounds__(NT) void topk_mask_kernel(const float* __restrict__ x,
                                                       float* __restrict__ out) {
    __shared__ u32 lkey[CAP];
    __shared__ u32 lidx[CAP];
    __shared__ u32 wcnt[8];       // ping-pong cross-wave counts (1 barrier/iter)
    __shared__ u32 lcount;
    __shared__ u32 s_tkey, s_cut;

    const int tid  = threadIdx.x;
    const int wid  = tid >> 6;
    const int lane = tid & 63;
    const u32 row  = blockIdx.x;

    const uint4* xr  = (const uint4*)(x + (size_t)row * HW);
    uint4*       orw = (uint4*)(out + (size_t)row * HW);

    // ---- load row into registers: 784 uint4 chunks; threads 0..15 take a 4th chunk
    const bool tail = (tid < 16);
    uint4 v0 = xr[tid];
    uint4 v1 = xr[tid + 256];
    uint4 v2 = xr[tid + 512];
    uint4 v3 = make_uint4(0u, 0u, 0u, 0u);
    if (tail) v3 = xr[tid + 768];

    const u32 i0 = (u32)tid * 4u;
    const u32 i1 = (u32)(tid + 256) * 4u;
    const u32 i2 = (u32)(tid + 512) * 4u;
    const u32 i3 = (u32)(tid + 768) * 4u;

    // ---- phase 1: block-wide MSB-first bit bisection until candidate set <= CAP
    u32 mask = 0u, prefix = 0u, rk = KSEL, active = HW;
    int bit = 30, it = 0;
    while (bit >= 0 && active > CAP) {
        const u32 m2  = mask | (1u << bit);
        const u32 tri = prefix | (1u << bit);
        const u32 c = cnt_match(v0, v1, v2, v3, tail, m2, tri);   // wave-uniform
        if (lane == 0) wcnt[((it & 1) << 2) + wid] = c;
        __syncthreads();
        const u32 b = (u32)((it & 1) << 2);
        const u32 c1 = wcnt[b] + wcnt[b + 1] + wcnt[b + 2] + wcnt[b + 3];
        mask = m2;
        if (c1 >= rk) { prefix = tri; active = c1; }
        else          { rk -= c1; active -= c1; }
        --bit; ++it;
    }

    if (active <= CAP) {
        // ---- compact matching candidates (key,idx) into LDS (<= CAP entries)
        if (tid == 0) lcount = 0u;
        __syncthreads();
#define EMIT(VAL, IDX, COND)                                                  \
        { const u32 _ka = (VAL) & 0x7fffffffu;                                \
          if ((COND) && ((_ka & mask) == prefix)) {                           \
              const u32 _s = atomicAdd(&lcount, 1u);                          \
              lkey[_s] = _ka; lidx[_s] = (IDX); } }
        EMIT(v0.x, i0 + 0u, true) EMIT(v0.y, i0 + 1u, true)
        EMIT(v0.z, i0 + 2u, true) EMIT(v0.w, i0 + 3u, true)
        EMIT(v1.x, i1 + 0u, true) EMIT(v1.y, i1 + 1u, true)
        EMIT(v1.z, i1 + 2u, true) EMIT(v1.w, i1 + 3u, true)
        EMIT(v2.x, i2 + 0u, true) EMIT(v2.y, i2 + 1u, true)
        EMIT(v2.z, i2 + 2u, true) EMIT(v2.w, i2 + 3u, true)
        EMIT(v3.x, i3 + 0u, tail) EMIT(v3.y, i3 + 1u, tail)
        EMIT(v3.z, i3 + 2u, tail) EMIT(v3.w, i3 + 3u, tail)
#undef EMIT
        __syncthreads();

        // ---- one finisher wave (rotated by row to spread across SIMDs) resolves
        //      remaining bits + tie cutoff with ballots only (no barriers inside)
        if (wid == (int)(row & 3u)) {
            const u32 Lc = lcount;    // == active
            u32 ek[8], ei[8];
#pragma unroll
            for (int j = 0; j < 8; ++j) {
                const u32 s = (u32)lane + (u32)(j << 6);
                const bool v = s < Lc;
                ek[j] = v ? lkey[s] : 0u;          // 0 never matches a trial (tri has a bit set)
                ei[j] = v ? lidx[s] : 0xffffffffu; // never counted as an equal index
            }
            while (bit >= 0 && active != rk) {
                const u32 m2  = mask | (1u << bit);
                const u32 tri = prefix | (1u << bit);
                u32 c1 = 0;
#pragma unroll
                for (int j = 0; j < 8; ++j)
                    c1 += __popcll(__ballot((ek[j] & m2) == tri));
                mask = m2;
                if (c1 >= rk) { prefix = tri; active = c1; }
                else          { rk -= c1; active -= c1; }
                --bit;
            }
            u32 tkey, cut;
            if (active == rk) {
                // keep the entire candidate set: threshold = min matching key, keep all equals
                u32 m = 0x7fffffffu;
#pragma unroll
                for (int j = 0; j < 8; ++j) {
                    const bool mt = ((ek[j] & mask) == prefix);
                    const u32 kk = mt ? ek[j] : 0x7fffffffu;
                    m = m < kk ? m : kk;
                }
#pragma unroll
                for (int o = 32; o >= 1; o >>= 1) {
                    const u32 t = (u32)__shfl_xor((int)m, o, 64);
                    m = m < t ? m : t;
                }
                tkey = m; cut = HW - 1u;
            } else {
                tkey = prefix;   // all 31 bits resolved
                // r-th smallest index among equals (all equals are in the list)
                u32 lo = 0u, hi = HW - 1u;
                while (lo < hi) {
                    const u32 mid = (lo + hi) >> 1;
                    u32 c = 0;
#pragma unroll
                    for (int j = 0; j < 8; ++j)
                        c += __popcll(__ballot(ek[j] == tkey && ei[j] <= mid));
                    if (c >= rk) hi = mid; else lo = mid + 1u;
                }
                cut = lo;
            }
            if (lane == 0) { s_tkey = tkey; s_cut = cut; }
        }
    } else {
        // ---- degenerate fallback: all 31 bits consumed with >CAP duplicates of tkey
        const u32 tkey = prefix;
        u32 lo = 0u, hi = HW - 1u;
        while (lo < hi) {
            const u32 mid = (lo + hi) >> 1;
            const u32 c = cnt_eq_le(v0, v1, v2, v3, tail, i0, i1, i2, i3, tkey, mid);
            if (lane == 0) wcnt[wid] = c;
            __syncthreads();
            const u32 c1 = wcnt[0] + wcnt[1] + wcnt[2] + wcnt[3];
            __syncthreads();
            if (c1 >= rk) hi = mid; else lo = mid + 1u;
        }
        if (tid == 0) { s_tkey = tkey; s_cut = lo; }
    }
    __syncthreads();

    const u32 TK = s_tkey;
    const u32 CO = s_cut;

    // ---- write output from registers (coalesced uint4 stores)
#define KEEPW(U, IX) ((((U) & 0x7fffffffu) > TK ||                             \
                       (((U) & 0x7fffffffu) == TK && (IX) <= CO)) ? (U) : 0u)
    uint4 o;
    o.x = KEEPW(v0.x, i0 + 0u); o.y = KEEPW(v0.y, i0 + 1u);
    o.z = KEEPW(v0.z, i0 + 2u); o.w = KEEPW(v0.w, i0 + 3u);
    orw[tid] = o;
    o.x = KEEPW(v1.x, i1 + 0u); o.y = KEEPW(v1.y, i1 + 1u);
    o.z = KEEPW(v1.z, i1 + 2u); o.w = KEEPW(v1.w, i1 + 3u);
    orw[tid + 256] = o;
    o.x = KEEPW(v2.x, i2 + 0u); o.y = KEEPW(v2.y, i2 + 1u);
    o.z = KEEPW(v2.z, i2 + 2u); o.w = KEEPW(v2.w, i2 + 3u);
    orw[tid + 512] = o;
    if (tail) {
        o.x = KEEPW(v3.x, i3 + 0u); o.y = KEEPW(v3.y, i3 + 1u);
        o.z = KEEPW(v3.z, i3 + 2u); o.w = KEEPW(v3.w, i3 + 3u);
        orw[tid + 768] = o;
    }
#undef KEEPW
}

extern "C" void kernel_launch(void* const* d_in, const int* in_sizes, int n_in,
                              void* d_out, int out_size, void* d_ws, size_t ws_size,
                              hipStream_t stream) {
    const float* x = (const float*)d_in[0];
    float* out = (float*)d_out;
    const int rows = in_sizes[0] / HW;   // 32 * 256 = 8192
    topk_mask_kernel<<<rows, NT, 0, stream>>>(x, out);
}

// Round 4
// 190.622 us; speedup vs baseline: 1.3275x; 1.0288x over previous
//
#include <hip/hip_runtime.h>

#define NT   256
#define HW   3136          // 56*56 = 64 lanes * 49 elements
#define KSEL 627u          // int(0.2 * 3136)
#define CAP  512           // per-row candidate list capacity

typedef unsigned int u32;
typedef unsigned long long u64;

__global__ __launch_bounds__(NT) void topk_mask_kernel(const float* __restrict__ x,
                                                       float* __restrict__ out) {
    // one wave per row; per-wave private LDS slices (no __syncthreads anywhere)
    __shared__ u32 lkey[4][CAP];
    __shared__ u32 lidx[4][CAP];
    __shared__ u32 lcnt[4];

    const int tid  = threadIdx.x;
    const int wid  = tid >> 6;
    const int lane = tid & 63;
    const u32 row  = blockIdx.x * 4u + (u32)wid;

    const uint4* xr = (const uint4*)(x + (size_t)row * HW);
    uint4*      orw = (uint4*)(out + (size_t)row * HW);

    // ---- load whole row into registers: 12 uint4/lane + 1 tail float/lane
    uint4 v[12];
#pragma unroll
    for (int j = 0; j < 12; ++j) v[j] = xr[lane + (j << 6)];
    const u32 tv = __float_as_uint(x[(size_t)row * HW + 3072 + lane]);

    // ---- phase 1: MSB-first bit bisection, wave-local (ballot+popc only)
    u32 mask = 0u, prefix = 0u, rk = KSEL, active = HW;
    int bit = 30;
    while (bit >= 0 && active > CAP) {
        const u32 m2  = mask | (1u << bit);
        const u32 tri = prefix | (1u << bit);
        u32 c = 0;
#pragma unroll
        for (int j = 0; j < 12; ++j) {
            c += __popcll(__ballot((v[j].x & m2) == tri));
            c += __popcll(__ballot((v[j].y & m2) == tri));
            c += __popcll(__ballot((v[j].z & m2) == tri));
            c += __popcll(__ballot((v[j].w & m2) == tri));
        }
        c += __popcll(__ballot((tv & m2) == tri));
        mask = m2;
        if (c >= rk) { prefix = tri; active = c; }
        else         { rk -= c; active -= c; }
        --bit;
    }

    u32 TK, CO;
    if (active <= CAP) {
        // ---- compact candidates into this wave's LDS slice (wave-local atomics)
        if (lane == 0) lcnt[wid] = 0u;
        u32* Lk = lkey[wid];
        u32* Li = lidx[wid];
#define EMIT(RAW, IDX) { const u32 _ka = (RAW) & 0x7fffffffu;                   \
        if ((_ka & mask) == prefix) { const u32 _s = atomicAdd(&lcnt[wid], 1u); \
            Lk[_s] = _ka; Li[_s] = (IDX); } }
#pragma unroll
        for (int j = 0; j < 12; ++j) {
            const u32 base = (u32)(lane << 2) + (u32)(j << 8);
            EMIT(v[j].x, base + 0u) EMIT(v[j].y, base + 1u)
            EMIT(v[j].z, base + 2u) EMIT(v[j].w, base + 3u)
        }
        EMIT(tv, 3072u + (u32)lane)
#undef EMIT
        __threadfence_block();   // order LDS reads below after the atomics/writes above
        const u32 Lc = lcnt[wid];
        u32 ek[8], ei[8];
#pragma unroll
        for (int j2 = 0; j2 < 8; ++j2) {
            const u32 s  = (u32)lane + (u32)(j2 << 6);
            const bool ok = s < Lc;
            ek[j2] = ok ? Lk[s] : 0u;           // 0 never matches a trial prefix
            ei[j2] = ok ? Li[s] : 0xffffffffu;  // never counted among equals
        }

        // ---- finish remaining bits on the compacted set (ballots only)
        while (bit >= 0 && active != rk) {
            const u32 m2  = mask | (1u << bit);
            const u32 tri = prefix | (1u << bit);
            u32 c = 0;
#pragma unroll
            for (int j2 = 0; j2 < 8; ++j2)
                c += __popcll(__ballot((ek[j2] & m2) == tri));
            mask = m2;
            if (c >= rk) { prefix = tri; active = c; }
            else         { rk -= c; active -= c; }
            --bit;
        }

        if (active == rk) {
            // keep the whole candidate set: threshold = min matching key, keep all equals
            u32 m = 0x7fffffffu;
#pragma unroll
            for (int j2 = 0; j2 < 8; ++j2) {
                const u32 kk = ((ek[j2] & mask) == prefix) ? ek[j2] : 0x7fffffffu;
                m = m < kk ? m : kk;
            }
#pragma unroll
            for (int o = 32; o >= 1; o >>= 1) {
                const u32 t = (u32)__shfl_xor((int)m, o, 64);
                m = m < t ? m : t;
            }
            TK = m; CO = HW - 1u;
        } else {
            // exact key resolved; find index cutoff of the rk-th equal (index order)
            TK = prefix;
            u64 eqm[8];
#pragma unroll
            for (int j2 = 0; j2 < 8; ++j2) eqm[j2] = __ballot(ek[j2] == TK);
            u32 lo = 0u, hi = HW - 1u;
            while (lo < hi) {
                const u32 mid = (lo + hi) >> 1;
                u32 c = 0;
#pragma unroll
                for (int j2 = 0; j2 < 8; ++j2)
                    c += __popcll(eqm[j2] & __ballot(ei[j2] <= mid));
                if (c >= rk) hi = mid; else lo = mid + 1u;
            }
            CO = lo;
        }
    } else {
        // ---- degenerate: >CAP duplicates of the exact key == prefix (all bits used)
        TK = prefix;
        u32 lo = 0u, hi = HW - 1u;
        while (lo < hi) {
            const u32 mid = (lo + hi) >> 1;
            u32 c = 0;
#pragma unroll
            for (int j = 0; j < 12; ++j) {
                const u32 base = (u32)(lane << 2) + (u32)(j << 8);
                c += __popcll(__ballot(((v[j].x & 0x7fffffffu) == TK) && (base + 0u) <= mid));
                c += __popcll(__ballot(((v[j].y & 0x7fffffffu) == TK) && (base + 1u) <= mid));
                c += __popcll(__ballot(((v[j].z & 0x7fffffffu) == TK) && (base + 2u) <= mid));
                c += __popcll(__ballot(((v[j].w & 0x7fffffffu) == TK) && (base + 3u) <= mid));
            }
            c += __popcll(__ballot(((tv & 0x7fffffffu) == TK) && (3072u + (u32)lane) <= mid));
            if (c >= rk) hi = mid; else lo = mid + 1u;
        }
        CO = lo;
    }

    // ---- write output from registers (coalesced uint4 stores)
#define KEEPW(U, IX) ((((U) & 0x7fffffffu) > TK ||                              \
                       (((U) & 0x7fffffffu) == TK && (IX) <= CO)) ? (U) : 0u)
#pragma unroll
    for (int j = 0; j < 12; ++j) {
        const u32 base = (u32)(lane << 2) + (u32)(j << 8);
        uint4 o;
        o.x = KEEPW(v[j].x, base + 0u);
        o.y = KEEPW(v[j].y, base + 1u);
        o.z = KEEPW(v[j].z, base + 2u);
        o.w = KEEPW(v[j].w, base + 3u);
        orw[lane + (j << 6)] = o;
    }
    out[(size_t)row * HW + 3072 + lane] = __uint_as_float(KEEPW(tv, 3072u + (u32)lane));
#undef KEEPW
}

extern "C" void kernel_launch(void* const* d_in, const int* in_sizes, int n_in,
                              void* d_out, int out_size, void* d_ws, size_t ws_size,
                              hipStream_t stream) {
    const float* x = (const float*)d_in[0];
    float* out = (float*)d_out;
    const int rows = in_sizes[0] / HW;       // 8192
    topk_mask_kernel<<<rows / 4, NT, 0, stream>>>(x, out);
}

// Round 5
// 182.101 us; speedup vs baseline: 1.3896x; 1.0468x over previous
//
#include <hip/hip_runtime.h>

#define NT   256
#define HW   3136          // 56*56 = 64 lanes * 49 elements
#define KSEL 627u          // int(0.2 * 3136)
#define CAP  512           // candidate list capacity
#define T1B  0x3F933333u   // ~1.15f  (seed bracket lo)
#define T2B  0x3FB9999Au   // ~1.45f  (seed bracket hi)

typedef unsigned int u32;
typedef unsigned long long u64;

__device__ __forceinline__ u32 prefix_cnt(u64 m) {   // #set bits below this lane
    return __builtin_amdgcn_mbcnt_hi((u32)(m >> 32),
           __builtin_amdgcn_mbcnt_lo((u32)m, 0u));
}

// count of elements with |f| >= tf across the wave's whole row (49/lane)
__device__ __forceinline__ u32 cnt_ge_all(const float4* v, float tvf, float tf) {
    u32 c = 0;
#pragma unroll
    for (int j = 0; j < 12; ++j) {
        c += (u32)__popcll(__ballot(__builtin_fabsf(v[j].x) >= tf));
        c += (u32)__popcll(__ballot(__builtin_fabsf(v[j].y) >= tf));
        c += (u32)__popcll(__ballot(__builtin_fabsf(v[j].z) >= tf));
        c += (u32)__popcll(__ballot(__builtin_fabsf(v[j].w) >= tf));
    }
    c += (u32)__popcll(__ballot(__builtin_fabsf(tvf) >= tf));
    return c;
}

__global__ __launch_bounds__(NT) void topk_mask_kernel(const float* __restrict__ x,
                                                       float* __restrict__ out) {
    __shared__ u32 LkA[4][CAP];   // per-wave candidate keys (|x| bits)
    __shared__ u32 LiA[4][CAP];   // per-wave candidate indices

    const int tid  = threadIdx.x;
    const int wid  = tid >> 6;
    const int lane = tid & 63;
    const u32 row  = blockIdx.x * 4u + (u32)wid;

    const float4* xr = (const float4*)(x + (size_t)row * HW);
    float4*      orw = (float4*)(out + (size_t)row * HW);

    float4 v[12];
#pragma unroll
    for (int j = 0; j < 12; ++j) v[j] = xr[lane + (j << 6)];
    const float tvf = x[(size_t)row * HW + 3072 + lane];

    u32* Lk = LkA[wid];
    u32* Li = LiA[wid];

    // ---- fused seed pass: counts at T1,T2 + optimistic compaction of [T1,T2)
    const float t1 = __uint_as_float(T1B);
    const float t2 = __uint_as_float(T2B);
    u32 c1 = 0, c2 = 0, base = 0;
#define PROC(F, IDX)                                                           \
    { const u64 m1 = __ballot(__builtin_fabsf(F) >= t1);                       \
      const u64 m2 = __ballot(__builtin_fabsf(F) >= t2);                       \
      c1 += (u32)__popcll(m1); c2 += (u32)__popcll(m2);                        \
      const u64 mb = m1 & ~m2;                                                 \
      if ((mb >> lane) & 1ull) {                                               \
          const u32 off = base + prefix_cnt(mb);                               \
          Lk[off] = __float_as_uint(F) & 0x7fffffffu; Li[off] = (IDX); }       \
      base += (u32)__popcll(mb); }
#pragma unroll
    for (int j = 0; j < 12; ++j) {
        const u32 bi = (u32)(lane << 2) + (u32)(j << 8);
        PROC(v[j].x, bi + 0u) PROC(v[j].y, bi + 1u)
        PROC(v[j].z, bi + 2u) PROC(v[j].w, bi + 3u)
    }
    PROC(tvf, 3072u + (u32)lane)
#undef PROC

    // ---- establish bracket [lo,hi) with cnt(>=lo)>=k>cnt(>=hi), active<=CAP
    u32 lo, hi, clo, chi, active;
    const bool seeded = (c1 >= KSEL) && (KSEL > c2);
    if (seeded && (c1 - c2) <= CAP) {
        lo = T1B; hi = T2B; clo = c1; chi = c2; active = c1 - c2;  // compaction valid
    } else {
        // general path (rare): midpoint bisection in key-bit space, float compares
        lo = 0u; clo = HW; hi = 0x80000000u; chi = 0u;
        if (c1 >= KSEL) {
            lo = T1B; clo = c1;
            if (c2 >= KSEL) { lo = T2B; clo = c2; }
            else            { hi = T2B; chi = c2; }
        } else { hi = T1B; chi = c1; }
        while (clo - chi > CAP && hi - lo > 1u) {
            const u32 mid = lo + ((hi - lo) >> 1);
            const u32 c = cnt_ge_all(v, tvf, __uint_as_float(mid));
            if (c >= KSEL) { lo = mid; clo = c; } else { hi = mid; chi = c; }
        }
        active = clo - chi;
        if (active <= CAP) {   // recompact with the final bracket
            base = 0;
            const float lof = __uint_as_float(lo), hif = __uint_as_float(hi);
#define PROC2(F, IDX)                                                          \
            { const u64 m1 = __ballot(__builtin_fabsf(F) >= lof);              \
              const u64 m2 = __ballot(__builtin_fabsf(F) >= hif);              \
              const u64 mb = m1 & ~m2;                                         \
              if ((mb >> lane) & 1ull) {                                       \
                  const u32 off = base + prefix_cnt(mb);                       \
                  Lk[off] = __float_as_uint(F) & 0x7fffffffu; Li[off] = (IDX); } \
              base += (u32)__popcll(mb); }
#pragma unroll
            for (int j = 0; j < 12; ++j) {
                const u32 bi = (u32)(lane << 2) + (u32)(j << 8);
                PROC2(v[j].x, bi + 0u) PROC2(v[j].y, bi + 1u)
                PROC2(v[j].z, bi + 2u) PROC2(v[j].w, bi + 3u)
            }
            PROC2(tvf, 3072u + (u32)lane)
#undef PROC2
        }
    }

    u32 TK, CO = HW - 1u;
    if (active > CAP) {
        // ---- degenerate: hi-lo==1 with >CAP duplicates of key 'lo' (never on real data)
        TK = lo;
        const u32 rk = KSEL - chi;
        u32 lo3 = 0u, hi3 = HW - 1u;
        while (lo3 < hi3) {
            const u32 mid = (lo3 + hi3) >> 1;
            u32 c = 0;
#pragma unroll
            for (int j = 0; j < 12; ++j) {
                const u32 bi = (u32)(lane << 2) + (u32)(j << 8);
                c += (u32)__popcll(__ballot(((__float_as_uint(v[j].x) & 0x7fffffffu) == TK) && (bi + 0u) <= mid));
                c += (u32)__popcll(__ballot(((__float_as_uint(v[j].y) & 0x7fffffffu) == TK) && (bi + 1u) <= mid));
                c += (u32)__popcll(__ballot(((__float_as_uint(v[j].z) & 0x7fffffffu) == TK) && (bi + 2u) <= mid));
                c += (u32)__popcll(__ballot(((__float_as_uint(v[j].w) & 0x7fffffffu) == TK) && (bi + 3u) <= mid));
            }
            c += (u32)__popcll(__ballot(((__float_as_uint(tvf) & 0x7fffffffu) == TK) && (3072u + (u32)lane) <= mid));
            if (c >= rk) hi3 = mid; else lo3 = mid + 1u;
        }
        CO = lo3;
    } else {
        // ---- finisher on compacted candidates (int-exact, wave-local, no barriers)
        const u32 Lc = active;
        const u32 rk = KSEL - chi;       // 1 <= rk <= Lc
        u32 ek[8];
#pragma unroll
        for (int j2 = 0; j2 < 8; ++j2) {
            const u32 s = (u32)lane + (u32)(j2 << 6);
            u32 kk = Lk[s];              // always in-bounds (CAP=512)
            ek[j2] = (s < Lc) ? kk : 0u; // pad 0: never >= any probe (probes >= 1)
        }
        u32 lo2 = lo, hi2 = hi;
        bool done = false;
        while (hi2 - lo2 > 1u) {
            const u32 mid = lo2 + ((hi2 - lo2) >> 1);
            u32 c = 0;
#pragma unroll
            for (int j2 = 0; j2 < 8; ++j2)
                c += (u32)__popcll(__ballot(ek[j2] >= mid));
            if (c == rk) {
                // exact hit: threshold = min candidate >= mid; keep-set = all of them
                u32 mn = 0xffffffffu;
#pragma unroll
                for (int j2 = 0; j2 < 8; ++j2) {
                    const u32 kk = (ek[j2] >= mid) ? ek[j2] : 0xffffffffu;
                    mn = mn < kk ? mn : kk;
                }
#pragma unroll
                for (int o = 32; o >= 1; o >>= 1) {
                    const u32 t = (u32)__shfl_xor((int)mn, o, 64);
                    mn = mn < t ? mn : t;
                }
                TK = mn; done = true; break;
            }
            if (c > rk) lo2 = mid; else hi2 = mid;
        }
        if (!done) {
            TK = lo2;
            u32 cgt = 0;
#pragma unroll
            for (int j2 = 0; j2 < 8; ++j2)
                cgt += (u32)__popcll(__ballot(ek[j2] > TK));   // pads: 0 > TK(>=0) false
            const u32 r = rk - cgt;                            // equals to keep, >= 1
            u32 eqs = 0;
#pragma unroll
            for (int j2 = 0; j2 < 8; ++j2)
                eqs += (u32)__popcll(__ballot(ek[j2] == TK && ((u32)lane + (u32)(j2 << 6)) < Lc));
            if (r != eqs) {
                // cold tie path: r-th smallest index among equals (all are in the list)
                u64 eqm[8]; u32 ei[8];
#pragma unroll
                for (int j2 = 0; j2 < 8; ++j2) {
                    const u32 s = (u32)lane + (u32)(j2 << 6);
                    eqm[j2] = __ballot(ek[j2] == TK && s < Lc);
                    ei[j2]  = Li[s];
                }
                u32 lo3 = 0u, hi3 = HW - 1u;
                while (lo3 < hi3) {
                    const u32 mid = (lo3 + hi3) >> 1;
                    u32 c = 0;
#pragma unroll
                    for (int j2 = 0; j2 < 8; ++j2)
                        c += (u32)__popcll(eqm[j2] & __ballot(ei[j2] <= mid));
                    if (c >= r) hi3 = mid; else lo3 = mid + 1u;
                }
                CO = lo3;
            }
        }
    }

    // ---- write output from registers (coalesced float4 stores)
    if (CO == HW - 1u) {   // dominant path: pure threshold, int-exact
#pragma unroll
        for (int j = 0; j < 12; ++j) {
            float4 o;
            o.x = ((__float_as_uint(v[j].x) & 0x7fffffffu) >= TK) ? v[j].x : 0.0f;
            o.y = ((__float_as_uint(v[j].y) & 0x7fffffffu) >= TK) ? v[j].y : 0.0f;
            o.z = ((__float_as_uint(v[j].z) & 0x7fffffffu) >= TK) ? v[j].z : 0.0f;
            o.w = ((__float_as_uint(v[j].w) & 0x7fffffffu) >= TK) ? v[j].w : 0.0f;
            orw[lane + (j << 6)] = o;
        }
        out[(size_t)row * HW + 3072 + lane] =
            (((__float_as_uint(tvf) & 0x7fffffffu) >= TK) ? tvf : 0.0f);
    } else {
#define KEEP(F, IDX) (((__float_as_uint(F) & 0x7fffffffu) > TK ||              \
                       ((__float_as_uint(F) & 0x7fffffffu) == TK && (IDX) <= CO)) ? (F) : 0.0f)
#pragma unroll
        for (int j = 0; j < 12; ++j) {
            const u32 bi = (u32)(lane << 2) + (u32)(j << 8);
            float4 o;
            o.x = KEEP(v[j].x, bi + 0u);
            o.y = KEEP(v[j].y, bi + 1u);
            o.z = KEEP(v[j].z, bi + 2u);
            o.w = KEEP(v[j].w, bi + 3u);
            orw[lane + (j << 6)] = o;
        }
        out[(size_t)row * HW + 3072 + lane] = KEEP(tvf, 3072u + (u32)lane);
#undef KEEP
    }
}

extern "C" void kernel_launch(void* const* d_in, const int* in_sizes, int n_in,
                              void* d_out, int out_size, void* d_ws, size_t ws_size,
                              hipStream_t stream) {
    const float* x = (const float*)d_in[0];
    float* out = (float*)d_out;
    const int rows = in_sizes[0] / HW;       // 8192
    topk_mask_kernel<<<rows / 4, NT, 0, stream>>>(x, out);
}